// Round 5
// baseline (125.014 us; speedup 1.0000x reference)
//
#include <hip/hip_runtime.h>
#include <cmath>

#define IMG_W 1024
#define PSTRIDE 1024          // plane col stride
#define PROWS 1020            // plane rows = image rows 4..1023

// separable Gaussian: w(ky,kx) = gv[ky]*gh[kx], 1/(8*pi) folded into gv
struct GK { float gh[7]; float gv[7]; };

// ---------------- K1: horizontal pass ----------------
// One image row per block (4 waves, 256 cols). Computes pointwise fields,
// exchanges via LDS (one barrier), 7-tap h-conv with premasked x-weights,
// stores 6 fields: p4 = (Hlo, Hhi, V, U), p2 = (Dlo, Dhi).
__global__ __launch_bounds__(256)
void mind_hpass(const float* __restrict__ img1, const float* __restrict__ img2,
                float4* __restrict__ p4, float2* __restrict__ p2, GK gk)
{
    __shared__ float4 buf[262];            // staged cols X0-3 .. X0+258

    const int tid = (int)threadIdx.x;
    const int X0  = 4 + 256 * (int)blockIdx.x;   // first output col of block
    const int r   = 4 + (int)blockIdx.y;         // source row, 4..1023
    const int rp  = r ^ 512;                     // the only in-bounds y-shift source

    const float* __restrict__ r2  = img2 + r  * IMG_W;
    const float* __restrict__ r2p = img2 + rp * IMG_W;
    const float* __restrict__ r1  = img1 + r  * IMG_W;
    const float* __restrict__ r1p = img1 + rp * IMG_W;

    // stage main col + (tid<6) one extra halo col
    #pragma unroll
    for (int e = 0; e < 2; ++e) {
        const int slot = (e == 0) ? tid : 256 + tid;
        const int scr  = X0 - 3 + slot;            // raw staged col
        if (e == 0 || tid < 6) {
            const int sc  = min(scr, 1023);        // clamp: garbage cols >=1024 masked later
            const int scp = sc ^ 512;              // the only in-bounds x-shift source
            const float a = r2[sc], b = r2[scp], c = r2p[sc], d = r2p[scp];
            const float u = r1[sc], ub = r1[scp], uc = r1p[sc];
            const float a2 = a * a;
            const float tb = a - b, tc = a - c, td = a - d;
            const float su = u - ub, sv = u - uc;
            float4 f;
            f.x = fmaf(tb, tb, -a2);                      // H: (a-b)^2 - a^2
            f.y = fmaf(tc, tc, -a2);                      // V
            f.z = fmaf(td, td, -a2);                      // D
            f.w = fmaf(u, u + u, fmaf(su, su, sv * sv));  // U: 4*Vimg integrand
            buf[slot] = f;
        }
    }
    __syncthreads();

    // premasked x-weights: tap kx of output col c=X0+tid touches col c-3+kx
    const int c = X0 + tid;
    float glx[7], ghx[7];
    #pragma unroll
    for (int kx = 0; kx < 7; ++kx) {
        const bool lo = (((c - 3 + kx) & 512) == 0);   // col<512 -> x-shift +1 valid
        glx[kx] = lo ? gk.gh[kx] : 0.f;
        ghx[kx] = lo ? 0.f : gk.gh[kx];
    }

    float hHlo = 0, hHhi = 0, hV = 0, hDlo = 0, hDhi = 0, hU = 0;
    #pragma unroll
    for (int kx = 0; kx < 7; ++kx) {
        const float4 g = buf[tid + kx];
        hHlo = fmaf(glx[kx],   g.x, hHlo);
        hHhi = fmaf(ghx[kx],   g.x, hHhi);
        hV   = fmaf(gk.gh[kx], g.y, hV);
        hDlo = fmaf(glx[kx],   g.z, hDlo);
        hDhi = fmaf(ghx[kx],   g.z, hDhi);
        hU   = fmaf(gk.gh[kx], g.w, hU);
    }

    if (c <= 1019) {                                  // cols 4..1019 stored
        const int idx = (r - 4) * PSTRIDE + c;
        p4[idx] = make_float4(hHlo, hHhi, hV, hU);
        p2[idx] = make_float2(hDlo, hDhi);
    }
}

// ---------------- K2: vertical pass + epilogue + reduction ----------------
__global__ __launch_bounds__(256)
void mind_vpass(const float4* __restrict__ p4, const float2* __restrict__ p2,
                float* __restrict__ out, GK gk)
{
    const int tx = (int)threadIdx.x, ty = (int)threadIdx.y;
    const int x = 7 + 64 * (int)blockIdx.x + tx;   // valid <= 1016
    const int y = 7 + 4 * (int)blockIdx.y + ty;    // valid <= 1017
    const bool ok = (x <= 1016) && (y <= 1017);
    const int xc = min(x, 1023);                   // clamp keeps reads in-array

    float Ph=0,Qh=0,Pv=0,Qv=0,Ppp=0,Ppm=0,Pmp=0,Pmm=0,V4=0;
    #pragma unroll
    for (int ky = 0; ky < 7; ++ky) {
        // plane row for image row (y-3+ky) is (y-3+ky)-4 = y-7+ky, in [0,1017]
        const int idx = (y - 7 + ky) * PSTRIDE + xc;
        const float4 a = p4[idx];
        const float2 b = p2[idx];
        const float g = gk.gv[ky];
        const bool ylo = (((y - 3 + ky) & 512) == 0);  // wave-uniform per ky
        const float wl = ylo ? g : 0.f;
        const float wh = ylo ? 0.f : g;
        Ph  = fmaf(g,  a.x, Ph);
        Qh  = fmaf(g,  a.y, Qh);
        Pv  = fmaf(wl, a.z, Pv);
        Qv  = fmaf(wh, a.z, Qv);
        V4  = fmaf(g,  a.w, V4);
        Ppp = fmaf(wl, b.x, Ppp);
        Ppm = fmaf(wh, b.x, Ppm);
        Pmp = fmaf(wl, b.y, Pmp);
        Pmm = fmaf(wh, b.y, Pmm);
    }

    const float V = fmaf(V4, 0.25f, 1e-5f);
    const float invV = 1.0f / V;
    float M = fminf(0.f, Ph);
    M = fminf(M, Qh);  M = fminf(M, Pv);  M = fminf(M, Qv);
    M = fminf(M, Ppp); M = fminf(M, Pmp); M = fminf(M, Ppm); M = fminf(M, Pmm);
    // sum over 80 shifts of exp(-(D_s - Dmin)/V); 72 far shifts share D = T0
    const float pix = 72.f * __expf(M * invV)
        + __expf((M - Ph ) * invV) + __expf((M - Qh ) * invV)
        + __expf((M - Pv ) * invV) + __expf((M - Qv ) * invV)
        + __expf((M - Ppp) * invV) + __expf((M - Pmp) * invV)
        + __expf((M - Ppm) * invV) + __expf((M - Pmm) * invV);
    float tsum = ok ? pix : 0.f;   // all exp args <= 0 -> finite even for garbage lanes

    #pragma unroll
    for (int off = 32; off > 0; off >>= 1)
        tsum += __shfl_down(tsum, off, 64);
    __shared__ float wsum[4];
    if (tx == 0) wsum[ty] = tsum;
    __syncthreads();
    if (tx == 0 && ty == 0) {
        const float bt = wsum[0] + wsum[1] + wsum[2] + wsum[3];
        atomicAdd(out, bt * (1.0f / 81688800.0f));   // 80 * 1011 * 1010
    }
}

extern "C" void kernel_launch(void* const* d_in, const int* in_sizes, int n_in,
                              void* d_out, int out_size, void* d_ws, size_t ws_size,
                              hipStream_t stream) {
    const float* img1 = (const float*)d_in[0];
    const float* img2 = (const float*)d_in[1];
    float* out = (float*)d_out;

    float4* p4 = (float4*)d_ws;                                  // 1020*1024*16 B
    float2* p2 = (float2*)((char*)d_ws + (size_t)PROWS * PSTRIDE * 16);

    GK gk;
    for (int i = 0; i < 7; ++i) {
        const double d = i - 3;
        gk.gh[i] = (float)std::exp(-(d * d) / 8.0);
        gk.gv[i] = (float)(std::exp(-(d * d) / 8.0) / (8.0 * M_PI));
    }

    hipMemsetAsync(d_out, 0, sizeof(float), stream);
    mind_hpass<<<dim3(4, PROWS), dim3(256), 0, stream>>>(img1, img2, p4, p2, gk);
    mind_vpass<<<dim3(16, 253), dim3(64, 4), 0, stream>>>(p4, p2, out, gk);
}

// Round 6
// 79.427 us; speedup vs baseline: 1.5739x; 1.5739x over previous
//
#include <hip/hip_runtime.h>
#include <cmath>

#define IMG_W 1024
#define SROWS 22              // staged source rows  (16 outputs + 6 halo)
#define SCOLS 70              // staged source cols  (64 outputs + 6 halo)

// separable Gaussian: w(ky,kx) = gv[ky]*gh[kx], 1/(8*pi) folded into gv
struct GK { float gh[7]; float gv[7]; };

__global__ __launch_bounds__(256)
void mind_tile(const float* __restrict__ img1, const float* __restrict__ img2,
               float* __restrict__ out, GK gk)
{
    __shared__ float4 s1[SROWS * SCOLS];    // 24640 B -> up to 6 blocks/CU

    const int tx  = (int)threadIdx.x;       // 0..63 : output col owner
    const int ty  = (int)threadIdx.y;       // 0..3  : 4-row group owner (== wave id)
    const int tid = ty * 64 + tx;
    const int x0  = 7 + 64 * (int)blockIdx.x;   // first output col of tile
    const int y0  = 7 + 16 * (int)blockIdx.y;   // first output row of tile

    // ---- stage 1: pointwise fields -> LDS (one pass, coalesced-ish) ----
    // H = (a-ax)^2 - a^2, V = (a-ay)^2 - a^2, D = (a-axy)^2 - a^2,
    // U = 2u^2 + (u-ux)^2 + (u-uy)^2   (the 4*Vimg integrand)
    #pragma unroll
    for (int k = 0; k < 7; ++k) {
        const int e = tid + 256 * k;
        if (e < SROWS * SCOLS) {
            const int r  = e / SCOLS;
            const int c  = e - r * SCOLS;
            const int sr = min(y0 - 3 + r, 1023);   // clamp feeds only masked outputs
            const int sc = min(x0 - 3 + c, 1023);
            const int srp = sr ^ 512;               // the only in-bounds y-shift source
            const int scp = sc ^ 512;               // the only in-bounds x-shift source
            const float a  = img2[sr  * IMG_W + sc ];
            const float b  = img2[sr  * IMG_W + scp];
            const float cc = img2[srp * IMG_W + sc ];
            const float d  = img2[srp * IMG_W + scp];
            const float u  = img1[sr  * IMG_W + sc ];
            const float ub = img1[sr  * IMG_W + scp];
            const float uc = img1[srp * IMG_W + sc ];
            const float a2 = a * a;
            const float tb = a - b, tc = a - cc, td = a - d;
            const float su = u - ub, sv = u - uc;
            float4 f;
            f.x = fmaf(tb, tb, -a2);
            f.y = fmaf(tc, tc, -a2);
            f.z = fmaf(td, td, -a2);
            f.w = fmaf(u, u + u, fmaf(su, su, sv * sv));
            s1[e] = f;
        }
    }
    __syncthreads();

    // premasked x-weights: tap kx of output col x0+tx touches source col x0-3+tx+kx
    float glx[7], ghx[7];
    #pragma unroll
    for (int kx = 0; kx < 7; ++kx) {
        const bool lo = (((x0 - 3 + tx + kx) & 512) == 0);  // col<512 -> +x shift valid
        glx[kx] = lo ? gk.gh[kx] : 0.f;
        ghx[kx] = lo ? 0.f : gk.gh[kx];
    }

    // ---- stage 2: per-thread fused h-conv + v-conv, all in registers ----
    // thread owns output rows y0+4*ty+o (o=0..3); needs s1 rows 4*ty .. 4*ty+9
    float Ph[4]  = {0,0,0,0}, Qh[4]  = {0,0,0,0}, Pv[4] = {0,0,0,0}, Qv[4] = {0,0,0,0};
    float Ppp[4] = {0,0,0,0}, Ppm[4] = {0,0,0,0}, Pmp[4] = {0,0,0,0}, Pmm[4] = {0,0,0,0};
    float V4[4]  = {0,0,0,0};

    #pragma unroll
    for (int r = 0; r < 10; ++r) {
        const float4* __restrict__ row = &s1[(4 * ty + r) * SCOLS + tx];
        float hHlo = 0, hHhi = 0, hV = 0, hDlo = 0, hDhi = 0, hU = 0;
        #pragma unroll
        for (int kx = 0; kx < 7; ++kx) {
            const float4 g = row[kx];               // ds_read_b128, imm offset
            hHlo = fmaf(glx[kx],   g.x, hHlo);
            hHhi = fmaf(ghx[kx],   g.x, hHhi);
            hV   = fmaf(gk.gh[kx], g.y, hV);
            hDlo = fmaf(glx[kx],   g.z, hDlo);
            hDhi = fmaf(ghx[kx],   g.z, hDhi);
            hU   = fmaf(gk.gh[kx], g.w, hU);
        }
        // y-mask of this source row (wave-uniform: ty fixed per wave)
        const bool ylo = (((y0 + 4 * ty - 3 + r) & 512) == 0);
        #pragma unroll
        for (int o = 0; o < 4; ++o) {
            if (r - o >= 0 && r - o <= 6) {         // compile-time pruned
                const float g  = gk.gv[r - o];
                const float wl = ylo ? g : 0.f;
                const float wh = ylo ? 0.f : g;
                Ph [o] = fmaf(g,  hHlo, Ph [o]);
                Qh [o] = fmaf(g,  hHhi, Qh [o]);
                Pv [o] = fmaf(wl, hV,   Pv [o]);
                Qv [o] = fmaf(wh, hV,   Qv [o]);
                Ppp[o] = fmaf(wl, hDlo, Ppp[o]);
                Ppm[o] = fmaf(wh, hDlo, Ppm[o]);
                Pmp[o] = fmaf(wl, hDhi, Pmp[o]);
                Pmm[o] = fmaf(wh, hDhi, Pmm[o]);
                V4 [o] = fmaf(g,  hU,   V4 [o]);
            }
        }
    }

    // ---- epilogue: 4 outputs per thread ----
    const bool xok = (x0 + tx <= 1016);
    float tsum = 0.f;
    #pragma unroll
    for (int o = 0; o < 4; ++o) {
        const float V = fmaf(V4[o], 0.25f, 1e-5f);
        const float invV = 1.0f / V;
        float M = fminf(0.f, Ph[o]);
        M = fminf(M, Qh[o]);  M = fminf(M, Pv[o]);  M = fminf(M, Qv[o]);
        M = fminf(M, Ppp[o]); M = fminf(M, Pmp[o]); M = fminf(M, Ppm[o]); M = fminf(M, Pmm[o]);
        // sum over 80 shifts of exp(-(D_s - Dmin)/V); 72 far shifts share D = T0
        const float pix = 72.f * __expf(M * invV)
            + __expf((M - Ph [o]) * invV) + __expf((M - Qh [o]) * invV)
            + __expf((M - Pv [o]) * invV) + __expf((M - Qv [o]) * invV)
            + __expf((M - Ppp[o]) * invV) + __expf((M - Pmp[o]) * invV)
            + __expf((M - Ppm[o]) * invV) + __expf((M - Pmm[o]) * invV);
        const bool ok = xok && (y0 + 4 * ty + o <= 1017);
        tsum += ok ? pix : 0.f;       // cndmask kills clamped-halo garbage (finite)
    }

    // ---- block reduction + one atomic ----
    #pragma unroll
    for (int off = 32; off > 0; off >>= 1)
        tsum += __shfl_down(tsum, off, 64);
    __shared__ float wsum[4];
    if (tx == 0) wsum[ty] = tsum;
    __syncthreads();
    if (tid == 0) {
        const float bt = wsum[0] + wsum[1] + wsum[2] + wsum[3];
        atomicAdd(out, bt * (1.0f / 81688800.0f));   // 80 * 1011 * 1010
    }
}

extern "C" void kernel_launch(void* const* d_in, const int* in_sizes, int n_in,
                              void* d_out, int out_size, void* d_ws, size_t ws_size,
                              hipStream_t stream) {
    const float* img1 = (const float*)d_in[0];
    const float* img2 = (const float*)d_in[1];
    float* out = (float*)d_out;

    GK gk;
    for (int i = 0; i < 7; ++i) {
        const double d = i - 3;
        gk.gh[i] = (float)std::exp(-(d * d) / 8.0);
        gk.gv[i] = (float)(std::exp(-(d * d) / 8.0) / (8.0 * M_PI));
    }

    hipMemsetAsync(d_out, 0, sizeof(float), stream);
    dim3 block(64, 4);
    dim3 grid(16, 64);   // 16*64=1024 >= 1010 cols ; 64*16=1024 >= 1011 rows
    mind_tile<<<grid, block, 0, stream>>>(img1, img2, out, gk);
}

// Round 7
// 70.771 us; speedup vs baseline: 1.7665x; 1.1223x over previous
//
#include <hip/hip_runtime.h>
#include <cmath>

#define IMG_W 1024
#define SROWS 22              // staged source rows  (16 outputs + 6 halo)
#define SCOLS 70              // staged source cols  (64 outputs + 6 halo)

// separable Gaussian: w(ky,kx) = gv[ky]*gh[kx], 1/(8*pi) folded into gv
struct GK { float gh[7]; float gv[7]; };

__device__ __forceinline__ float warp_block_sum(float v, float* wsum, int tx, int ty) {
    #pragma unroll
    for (int off = 32; off > 0; off >>= 1)
        v += __shfl_down(v, off, 64);
    if (tx == 0) wsum[ty] = v;
    __syncthreads();
    return wsum[0] + wsum[1] + wsum[2] + wsum[3];
}

__global__ __launch_bounds__(256)
void mind_tile(const float* __restrict__ img1, const float* __restrict__ img2,
               float* __restrict__ partials, GK gk)
{
    __shared__ float4 s1[SROWS * SCOLS];    // 24640 B

    const int tx  = (int)threadIdx.x;       // 0..63 : output col owner
    const int ty  = (int)threadIdx.y;       // 0..3  : 4-row group owner (== wave id)
    const int tid = ty * 64 + tx;
    const int x0  = 7 + 64 * (int)blockIdx.x;   // first output col of tile
    const int y0  = 7 + 16 * (int)blockIdx.y;   // first output row of tile

    // ---- stage 1: pointwise fields -> LDS ----
    #pragma unroll
    for (int k = 0; k < 7; ++k) {
        const int e = tid + 256 * k;
        if (e < SROWS * SCOLS) {
            const int r  = e / SCOLS;
            const int c  = e - r * SCOLS;
            const int sr = min(y0 - 3 + r, 1023);   // clamp feeds only masked outputs
            const int sc = min(x0 - 3 + c, 1023);
            const int srp = sr ^ 512;               // the only in-bounds y-shift source
            const int scp = sc ^ 512;               // the only in-bounds x-shift source
            const float a  = img2[sr  * IMG_W + sc ];
            const float b  = img2[sr  * IMG_W + scp];
            const float cc = img2[srp * IMG_W + sc ];
            const float d  = img2[srp * IMG_W + scp];
            const float u  = img1[sr  * IMG_W + sc ];
            const float ub = img1[sr  * IMG_W + scp];
            const float uc = img1[srp * IMG_W + sc ];
            const float a2 = a * a;
            const float tb = a - b, tc = a - cc, td = a - d;
            const float su = u - ub, sv = u - uc;
            float4 f;
            f.x = fmaf(tb, tb, -a2);                      // H
            f.y = fmaf(tc, tc, -a2);                      // V
            f.z = fmaf(td, td, -a2);                      // D
            f.w = fmaf(u, u + u, fmaf(su, su, sv * sv));  // U (4*Vimg integrand)
            s1[e] = f;
        }
    }
    __syncthreads();

    // x/y mask-split detection: boundary lies between 511 and 512
    const bool xs = (x0 - 3 <= 511) && (x0 + 66 >= 512);   // only bx==7
    const bool ys = (y0 - 3 <= 511) && (y0 + 18 >= 512);   // only by==31
    const bool xok = (x0 + tx <= 1016);
    float tsum = 0.f;

    if (!xs && !ys) {
        // ================= FAST path: block-uniform masks (92% of blocks) ======
        const bool xlo = ((x0 & 512) == 0);    // whole block same x-side
        const bool ylo = ((y0 & 512) == 0);    // whole block same y-side
        float Px[4] = {0,0,0,0}, Py[4] = {0,0,0,0}, Pd[4] = {0,0,0,0}, V4[4] = {0,0,0,0};
        #pragma unroll
        for (int r = 0; r < 10; ++r) {
            const float4* __restrict__ row = &s1[(4 * ty + r) * SCOLS + tx];
            float hH = 0, hV = 0, hD = 0, hU = 0;
            #pragma unroll
            for (int kx = 0; kx < 7; ++kx) {
                const float4 g = row[kx];
                hH = fmaf(gk.gh[kx], g.x, hH);
                hV = fmaf(gk.gh[kx], g.y, hV);
                hD = fmaf(gk.gh[kx], g.z, hD);
                hU = fmaf(gk.gh[kx], g.w, hU);
            }
            #pragma unroll
            for (int o = 0; o < 4; ++o) {
                if (r - o >= 0 && r - o <= 6) {          // compile-time pruned
                    const float g = gk.gv[r - o];
                    Px[o] = fmaf(g, hH, Px[o]);
                    Py[o] = fmaf(g, hV, Py[o]);
                    Pd[o] = fmaf(g, hD, Pd[o]);
                    V4[o] = fmaf(g, hU, V4[o]);
                }
            }
        }
        (void)xlo; (void)ylo;  // epilogue below is side-independent
        #pragma unroll
        for (int o = 0; o < 4; ++o) {
            const float V = fmaf(V4[o], 0.25f, 1e-5f);
            const float invV = 1.0f / V;
            float M = fminf(0.f, Px[o]);
            M = fminf(M, Py[o]); M = fminf(M, Pd[o]);
            // 5 of the 8 near-shift maps equal T0 here -> join the 72 far shifts
            const float pix = 77.f * __expf(M * invV)
                + __expf((M - Px[o]) * invV)
                + __expf((M - Py[o]) * invV)
                + __expf((M - Pd[o]) * invV);
            const bool ok = xok && (y0 + 4 * ty + o <= 1017);
            tsum += ok ? pix : 0.f;
        }
    } else {
        // ================= GENERAL path: boundary-straddling blocks ============
        float glx[7], ghx[7];
        #pragma unroll
        for (int kx = 0; kx < 7; ++kx) {
            const bool lo = (((x0 - 3 + tx + kx) & 512) == 0);
            glx[kx] = lo ? gk.gh[kx] : 0.f;
            ghx[kx] = lo ? 0.f : gk.gh[kx];
        }
        float Ph[4]  = {0,0,0,0}, Qh[4]  = {0,0,0,0}, Pv[4] = {0,0,0,0}, Qv[4] = {0,0,0,0};
        float Ppp[4] = {0,0,0,0}, Ppm[4] = {0,0,0,0}, Pmp[4] = {0,0,0,0}, Pmm[4] = {0,0,0,0};
        float V4[4]  = {0,0,0,0};
        #pragma unroll
        for (int r = 0; r < 10; ++r) {
            const float4* __restrict__ row = &s1[(4 * ty + r) * SCOLS + tx];
            float hHlo = 0, hHhi = 0, hV = 0, hDlo = 0, hDhi = 0, hU = 0;
            #pragma unroll
            for (int kx = 0; kx < 7; ++kx) {
                const float4 g = row[kx];
                hHlo = fmaf(glx[kx],   g.x, hHlo);
                hHhi = fmaf(ghx[kx],   g.x, hHhi);
                hV   = fmaf(gk.gh[kx], g.y, hV);
                hDlo = fmaf(glx[kx],   g.z, hDlo);
                hDhi = fmaf(ghx[kx],   g.z, hDhi);
                hU   = fmaf(gk.gh[kx], g.w, hU);
            }
            const bool ylo = (((y0 + 4 * ty - 3 + r) & 512) == 0);
            #pragma unroll
            for (int o = 0; o < 4; ++o) {
                if (r - o >= 0 && r - o <= 6) {
                    const float g  = gk.gv[r - o];
                    const float wl = ylo ? g : 0.f;
                    const float wh = ylo ? 0.f : g;
                    Ph [o] = fmaf(g,  hHlo, Ph [o]);
                    Qh [o] = fmaf(g,  hHhi, Qh [o]);
                    Pv [o] = fmaf(wl, hV,   Pv [o]);
                    Qv [o] = fmaf(wh, hV,   Qv [o]);
                    Ppp[o] = fmaf(wl, hDlo, Ppp[o]);
                    Ppm[o] = fmaf(wh, hDlo, Ppm[o]);
                    Pmp[o] = fmaf(wl, hDhi, Pmp[o]);
                    Pmm[o] = fmaf(wh, hDhi, Pmm[o]);
                    V4 [o] = fmaf(g,  hU,   V4 [o]);
                }
            }
        }
        #pragma unroll
        for (int o = 0; o < 4; ++o) {
            const float V = fmaf(V4[o], 0.25f, 1e-5f);
            const float invV = 1.0f / V;
            float M = fminf(0.f, Ph[o]);
            M = fminf(M, Qh[o]);  M = fminf(M, Pv[o]);  M = fminf(M, Qv[o]);
            M = fminf(M, Ppp[o]); M = fminf(M, Pmp[o]); M = fminf(M, Ppm[o]); M = fminf(M, Pmm[o]);
            const float pix = 72.f * __expf(M * invV)
                + __expf((M - Ph [o]) * invV) + __expf((M - Qh [o]) * invV)
                + __expf((M - Pv [o]) * invV) + __expf((M - Qv [o]) * invV)
                + __expf((M - Ppp[o]) * invV) + __expf((M - Pmp[o]) * invV)
                + __expf((M - Ppm[o]) * invV) + __expf((M - Pmm[o]) * invV);
            const bool ok = xok && (y0 + 4 * ty + o <= 1017);
            tsum += ok ? pix : 0.f;
        }
    }

    // ---- per-block partial to workspace (NO same-address atomics) ----
    __shared__ float wsum[4];
    const float bt = warp_block_sum(tsum, wsum, tx, ty);
    if (tid == 0)
        partials[(int)blockIdx.y * gridDim.x + (int)blockIdx.x] = bt;
}

__global__ __launch_bounds__(256)
void mind_reduce(const float* __restrict__ partials, float* __restrict__ out)
{
    // 1024 partials, one block
    float s = 0.f;
    #pragma unroll
    for (int k = 0; k < 4; ++k)
        s += partials[(int)threadIdx.x + 256 * k];
    double d = (double)s;
    #pragma unroll
    for (int off = 32; off > 0; off >>= 1)
        d += __shfl_down(d, off, 64);
    __shared__ double sm[4];
    const int lane = (int)threadIdx.x & 63, wid = (int)threadIdx.x >> 6;
    if (lane == 0) sm[wid] = d;
    __syncthreads();
    if (threadIdx.x == 0)
        out[0] = (float)((sm[0] + sm[1] + sm[2] + sm[3]) / 81688800.0);  // 80*1011*1010
}

extern "C" void kernel_launch(void* const* d_in, const int* in_sizes, int n_in,
                              void* d_out, int out_size, void* d_ws, size_t ws_size,
                              hipStream_t stream) {
    const float* img1 = (const float*)d_in[0];
    const float* img2 = (const float*)d_in[1];
    float* out = (float*)d_out;
    float* partials = (float*)d_ws;

    GK gk;
    for (int i = 0; i < 7; ++i) {
        const double d = i - 3;
        gk.gh[i] = (float)std::exp(-(d * d) / 8.0);
        gk.gv[i] = (float)(std::exp(-(d * d) / 8.0) / (8.0 * M_PI));
    }

    dim3 block(64, 4);
    dim3 grid(16, 64);   // 16*64=1024 blocks
    mind_tile<<<grid, block, 0, stream>>>(img1, img2, partials, gk);
    mind_reduce<<<1, 256, 0, stream>>>(partials, out);
}